// Round 10
// baseline (102.402 us; speedup 1.0000x reference)
//
#include <hip/hip_runtime.h>
#include <cfloat>

#define NFEAT 256
#define BATCH 4096
#define MTOT  16384
#define NSTRIP 16
#define STRIPW 1024
#define NH 32                 // 32-col chunks per strip
#define UMARGIN 0.75f

typedef __attribute__((ext_vector_type(8))) short bf16x8;
typedef __attribute__((ext_vector_type(4))) float f32x4;

#define GP(p)   ((const __attribute__((address_space(1))) void*)(p))
#define LDSP(p) ((__attribute__((address_space(3))) void*)(p))

__device__ __forceinline__ unsigned bf16pack(float a, float b) {
    unsigned ua = __float_as_uint(a), ub = __float_as_uint(b);
    unsigned ra = (ua + 0x7fffu + ((ua >> 16) & 1u)) >> 16;
    unsigned rb = (ub + 0x7fffu + ((ub >> 16) & 1u)) >> 16;
    return ra | (rb << 16);
}

// ---------------------------------------------------------------------------
// Prep (fused): fp32->bf16 + squared norm for both w and xb. 1 wave per row.
// ---------------------------------------------------------------------------
__global__ __launch_bounds__(256) void prep_kernel(const float* __restrict__ xb,
                                                   const float* __restrict__ w,
                                                   uint2* __restrict__ Abf,
                                                   uint2* __restrict__ Bbf,
                                                   float* __restrict__ a2,
                                                   float* __restrict__ b2) {
    int gid  = blockIdx.x * blockDim.x + threadIdx.x;
    int row  = gid >> 6;
    int lane = gid & 63;
    const float* src;
    uint2* dst;
    float* nrm;
    if (row < MTOT) {
        src = w + (size_t)row * NFEAT;  dst = Bbf + (size_t)row * 64;  nrm = b2 + row;
    } else {
        int r = row - MTOT;
        src = xb + (size_t)r * NFEAT;   dst = Abf + (size_t)r * 64;    nrm = a2 + r;
    }
    float4 v = ((const float4*)src)[lane];
    dst[lane] = make_uint2(bf16pack(v.x, v.y), bf16pack(v.z, v.w));
    float s = v.x * v.x + v.y * v.y + v.z * v.z + v.w * v.w;
    #pragma unroll
    for (int off = 32; off > 0; off >>= 1) s += __shfl_down(s, off);
    if (lane == 0) *nrm = s;
}

// ---------------------------------------------------------------------------
// Main: 3-deep-ring, ONE-barrier-per-chunk MFMA distance GEMM.
// Grid 512 = 32 m-tiles x 16 strips (2 strips/XCD); block 256 = 4 waves
// stacked on ROWS (wave tile 32 rows x 32 cols -> no cross-wave merge).
// A panel afr[2][8] (64 VGPR) in regs. LDS = 3 x 16 KB ring + b2 4 KB = 52 KB
// (2 blocks/CU). Per chunk h: vmcnt(4) -> barrier -> issue stage(h+2) into
// the slot whose readers finished at h-1 (single-barrier-safe) -> ds_read +
// 32 MFMA (setprio) -> top-2 fold. SKEL=1 variant: no staging/fold (asm-kept
// acc) -> isolates the sync'd MFMA core cost (ablation probe, scratch out).
// min-dist == max-(dot - b2/2); per-lane top-2 with 6-bit mantissa-packed id.
// ---------------------------------------------------------------------------
template<int SKEL>
__global__ __launch_bounds__(256, 2) void som_core(
        const unsigned short* __restrict__ Abf, const unsigned short* __restrict__ Bbf,
        const float* __restrict__ b2, float* __restrict__ part, float* __restrict__ dbg) {
    __shared__ char smem[53248];    // ring 3 x 16K | b2 strip 4K

    const int t = threadIdx.x, l = t & 63;
    const int wid = t >> 6;                    // wave = 32-row band
    const int x = blockIdx.x & 7, y = blockIdx.x >> 3;
    const int strip = x * 2 + (y >> 5);        // 2 strips per XCD
    const int m0 = (y & 31) * 128;
    const int ns0 = strip * STRIPW;

    // ---- A panel -> 64 true VGPRs (frag layout), loaded + pinned ----
    const char* gA = (const char*)Abf
                   + (size_t)(m0 + wid * 32 + (l & 15)) * 512 + (l >> 4) * 16;
    bf16x8 afr[2][8];
    #pragma unroll
    for (int mf = 0; mf < 2; ++mf)
        #pragma unroll
        for (int kk = 0; kk < 8; ++kk)
            afr[mf][kk] = *(const bf16x8*)(gA + (size_t)mf * 16 * 512 + kk * 64);
    #pragma unroll
    for (int mf = 0; mf < 2; ++mf)
        #pragma unroll
        for (int kk = 0; kk < 8; ++kk)
            asm volatile("" : "+v"(afr[mf][kk]));

    // ---- staging: chunk = 32 cols x 512 B = 16 KB = 4 ops/thread ----
    // op i: col = i*8 + (t>>5), in-col byte (t&31)*16, swizzle ((col&7)<<4)
    // pre-applied to the SOURCE (LDS dest linear, T21 both-sides rule).
    const int sbyte = ((t & 31) * 16) ^ ((t >> 5) << 4);
    const char* gBs = (const char*)Bbf + (size_t)(ns0 + (t >> 5)) * 512 + sbyte;
#define STAGE(dstb, c) {                                                         \
        const char* s_ = gBs + (size_t)(c) * 16384;                              \
        char* d_ = (dstb) + t * 16;                                              \
        __builtin_amdgcn_global_load_lds(GP(s_),         LDSP(d_),         16,0,0); \
        __builtin_amdgcn_global_load_lds(GP(s_ + 4096),  LDSP(d_ + 4096),  16,0,0); \
        __builtin_amdgcn_global_load_lds(GP(s_ + 8192),  LDSP(d_ + 8192),  16,0,0); \
        __builtin_amdgcn_global_load_lds(GP(s_ + 12288), LDSP(d_ + 12288), 16,0,0); }

    // prologue: b2 strip (1 op) then chunks 0,1 -> slots 0,1 (9 in flight)
    __builtin_amdgcn_global_load_lds(GP((const char*)b2 + (size_t)ns0 * 4 + t * 16),
                                     LDSP(smem + 49152 + t * 16), 16, 0, 0);
    STAGE(smem,         0)
    STAGE(smem + 16384, 1)

    float r0[2][4], r1[2][4];
    #pragma unroll
    for (int mf = 0; mf < 2; ++mf)
        #pragma unroll
        for (int j = 0; j < 4; ++j) { r0[mf][j] = -FLT_MAX; r1[mf][j] = -FLT_MAX; }

    char* pr = smem;                 // read slot (chunk h)
    char* pm = smem + 16384;         // next     (chunk h+1)
    char* ps = smem + 32768;         // stage target (chunk h+2)
    const int rswz = (l & 7) << 4;
    const int cb = (l & 15) * 512;

    for (int h = 0; h < NH; ++h) {
        if (h < NH - 1) asm volatile("s_waitcnt vmcnt(4)" ::: "memory");
        else            asm volatile("s_waitcnt vmcnt(0)" ::: "memory");
        __builtin_amdgcn_s_barrier();   // chunk h visible; h-1 readers done
        asm volatile("" ::: "memory");

        if (h + 2 < NH) STAGE(ps, h + 2)   // slot freed by compute(h-1)

        f32x4 acc[2][2];
        if constexpr (!SKEL) {
            const int c0 = h * 32 + (l & 15);
            const float b20 = -0.5f * *(const float*)(smem + 49152 + c0 * 4);
            const float b21 = -0.5f * *(const float*)(smem + 49152 + c0 * 4 + 64);
            #pragma unroll
            for (int mf = 0; mf < 2; ++mf) {
                acc[mf][0] = (f32x4){b20, b20, b20, b20};
                acc[mf][1] = (f32x4){b21, b21, b21, b21};
            }
        } else {
            #pragma unroll
            for (int mf = 0; mf < 2; ++mf)
                #pragma unroll
                for (int nf = 0; nf < 2; ++nf)
                    acc[mf][nf] = (f32x4){0.f, 0.f, 0.f, 0.f};
        }

        __builtin_amdgcn_s_setprio(1);
        #pragma unroll
        for (int kk = 0; kk < 8; ++kk) {
            const int ko = (kk * 64 + (l >> 4) * 16) ^ rswz;
            bf16x8 bf0 = *(const bf16x8*)(pr + cb + ko);
            bf16x8 bf1 = *(const bf16x8*)(pr + 8192 + cb + ko);
            #pragma unroll
            for (int mf = 0; mf < 2; ++mf) {
                acc[mf][0] = __builtin_amdgcn_mfma_f32_16x16x32_bf16(afr[mf][kk], bf0, acc[mf][0], 0, 0, 0);
                acc[mf][1] = __builtin_amdgcn_mfma_f32_16x16x32_bf16(afr[mf][kk], bf1, acc[mf][1], 0, 0, 0);
            }
        }
        __builtin_amdgcn_s_setprio(0);

        if constexpr (!SKEL) {
            // top-2 fold: 6-bit id (h*2 + nf) in low mantissa bits
            #pragma unroll
            for (int nf = 0; nf < 2; ++nf) {
                const unsigned idn = (unsigned)(h * 2 + nf);
                #pragma unroll
                for (int mf = 0; mf < 2; ++mf)
                    #pragma unroll
                    for (int j = 0; j < 4; ++j) {
                        float p = __uint_as_float((__float_as_uint(acc[mf][nf][j]) & 0xFFFFFFC0u) | idn);
                        float nr1 = __builtin_amdgcn_fmed3f(r0[mf][j], r1[mf][j], p);
                        r0[mf][j] = fmaxf(r0[mf][j], p);
                        r1[mf][j] = nr1;
                    }
            }
        } else {
            asm volatile("" :: "v"(acc[0][0]), "v"(acc[0][1]),
                               "v"(acc[1][0]), "v"(acc[1][1]));   // keep MFMAs live
            #pragma unroll
            for (int mf = 0; mf < 2; ++mf)
                #pragma unroll
                for (int j = 0; j < 4; ++j) r0[mf][j] += acc[mf][0][j];
        }

        char* tp = pr; pr = pm; pm = ps; ps = tp;   // rotate ring
    }

    if constexpr (SKEL) {
        dbg[(size_t)blockIdx.x * 256 + t] = r0[0][0] + r0[1][3];
        return;
    }

    // ---- per-row merge over 16 lane-cols; leaders write part directly ----
    #pragma unroll
    for (int mf = 0; mf < 2; ++mf)
        #pragma unroll
        for (int j = 0; j < 4; ++j) {
            unsigned u0 = __float_as_uint(r0[mf][j]);
            unsigned u1 = __float_as_uint(r1[mf][j]);
            u0 = (u0 & 0xFFFFFC00u) | ((u0 & 63u) << 4) | (unsigned)(l & 15);
            u1 = (u1 & 0xFFFFFC00u) | ((u1 & 63u) << 4) | (unsigned)(l & 15);
            float v0 = __uint_as_float(u0), v1 = __uint_as_float(u1);
            #pragma unroll
            for (int off = 1; off < 16; off <<= 1) {
                float o0 = __shfl_xor(v0, off), o1 = __shfl_xor(v1, off);
                float nv1 = fmaxf(fminf(v0, o0), fmaxf(v1, o1));
                v0 = fmaxf(v0, o0);
                v1 = nv1;
            }
            if ((l & 15) == 0) {
                int row = m0 + wid * 32 + mf * 16 + (l >> 4) * 4 + j;
                ((float2*)part)[(size_t)row * NSTRIP + strip] = make_float2(v0, v1);
            }
        }
#undef STAGE
}

// ---------------------------------------------------------------------------
// Refine: 1 wave per row over 32 packed entries; exact fp32+sqrt recompute of
// candidates within margin; lexicographic (dist, idx) argmin.
// ---------------------------------------------------------------------------
__global__ __launch_bounds__(256) void refine_kernel(
        const float* __restrict__ xb, const float* __restrict__ w,
        const float* __restrict__ a2, const float* __restrict__ b2,
        const float* __restrict__ part, int* __restrict__ out) {
    const int t = threadIdx.x, l = t & 63;
    const int row = blockIdx.x * 4 + (t >> 6);

    const float* pr = part + (size_t)row * (NSTRIP * 2);
    float v = (l < NSTRIP * 2) ? pr[l] : -FLT_MAX;
    float mx = v;
    #pragma unroll
    for (int off = 1; off < 64; off <<= 1) mx = fmaxf(mx, __shfl_xor(mx, off));
    const float cut = mx - UMARGIN;

    unsigned long long key = ~0ull;
    if (l < NSTRIP * 2 && v >= cut) {
        unsigned b = __float_as_uint(v);
        int lane4 = b & 15, id6 = (b >> 4) & 63;
        int col = (l >> 1) * STRIPW + (id6 >> 1) * 32 + (id6 & 1) * 16 + lane4;
        const float4* xr = (const float4*)(xb + (size_t)row * NFEAT);
        const float4* wr = (const float4*)(w + (size_t)col * NFEAT);
        float s0 = 0.f, s1 = 0.f, s2 = 0.f, s3 = 0.f;
        #pragma unroll
        for (int k = 0; k < 16; ++k) {
            float4 x0 = xr[4 * k + 0], w0 = wr[4 * k + 0];
            float4 x1 = xr[4 * k + 1], w1 = wr[4 * k + 1];
            float4 x2 = xr[4 * k + 2], w2 = wr[4 * k + 2];
            float4 x3 = xr[4 * k + 3], w3 = wr[4 * k + 3];
            s0 += x0.x * w0.x + x0.y * w0.y + x0.z * w0.z + x0.w * w0.w;
            s1 += x1.x * w1.x + x1.y * w1.y + x1.z * w1.z + x1.w * w1.w;
            s2 += x2.x * w2.x + x2.y * w2.y + x2.z * w2.z + x2.w * w2.w;
            s3 += x3.x * w3.x + x3.y * w3.y + x3.z * w3.z + x3.w * w3.w;
        }
        float dot = (s0 + s1) + (s2 + s3);
        float dd = a2[row] + b2[col] - 2.f * dot;
        float s = sqrtf(fmaxf(dd, 0.f));
        key = ((unsigned long long)__float_as_uint(s) << 32) | (unsigned)col;
    }
    #pragma unroll
    for (int off = 1; off < 64; off <<= 1) {
        unsigned long long o = __shfl_xor(key, off);
        key = o < key ? o : key;
    }
    if (l == 0) {
        int idx = (int)(key & 0xffffffffu);
        out[2 * row]     = idx >> 7;
        out[2 * row + 1] = idx & 127;
    }
}

extern "C" void kernel_launch(void* const* d_in, const int* in_sizes, int n_in,
                              void* d_out, int out_size, void* d_ws, size_t ws_size,
                              hipStream_t stream) {
    const float* xb = (const float*)d_in[0];   // (4096, 256)
    const float* w  = (const float*)d_in[1];   // (16384, 256)
    int* out = (int*)d_out;

    char* ws = (char*)d_ws;
    unsigned short* Abf = (unsigned short*)ws;                 // 2 MB
    unsigned short* Bbf = (unsigned short*)(ws + (2u << 20));  // 8 MB
    float* a2   = (float*)(ws + (10u << 20));                  // 16 KB
    float* b2   = (float*)(ws + (10u << 20) + (64u << 10));    // 64 KB
    float* part = (float*)(ws + (10u << 20) + (128u << 10));   // 512 KB
    float* dbg  = (float*)(ws + (12u << 20));                  // 512 KB probe sink

    prep_kernel<<<((MTOT + BATCH) * 64) / 256, 256, 0, stream>>>(xb, w, (uint2*)Abf,
                                                                 (uint2*)Bbf, a2, b2);
    som_core<0><<<512, 256, 0, stream>>>(Abf, Bbf, b2, part, dbg);
    refine_kernel<<<BATCH / 4, 256, 0, stream>>>(xb, w, a2, b2, part, out);
    // ablation probe: sync'd MFMA core only (no staging, no fold) -> scratch
    som_core<1><<<512, 256, 0, stream>>>(Abf, Bbf, b2, part, dbg);
}

// Round 11
// 77.858 us; speedup vs baseline: 1.3152x; 1.3152x over previous
//
#include <hip/hip_runtime.h>
#include <cfloat>

#define NFEAT 256
#define BATCH 4096
#define MTOT  16384
#define NSTRIP 32
#define STRIPW 512
#define NCH 32                // 16-col chunks per strip
#define UMARGIN 0.75f

typedef __attribute__((ext_vector_type(8))) short bf16x8;
typedef __attribute__((ext_vector_type(4))) float f32x4;

__device__ __forceinline__ unsigned bf16pack(float a, float b) {
    unsigned ua = __float_as_uint(a), ub = __float_as_uint(b);
    unsigned ra = (ua + 0x7fffu + ((ua >> 16) & 1u)) >> 16;
    unsigned rb = (ub + 0x7fffu + ((ub >> 16) & 1u)) >> 16;
    return ra | (rb << 16);
}

// ---------------------------------------------------------------------------
// Prep A: xb -> bf16 row-major + a2. One wave per row.
// ---------------------------------------------------------------------------
__global__ __launch_bounds__(256) void prep_a_kernel(const float* __restrict__ xb,
                                                     uint2* __restrict__ Abf,
                                                     float* __restrict__ a2) {
    int gid  = blockIdx.x * blockDim.x + threadIdx.x;
    int row  = gid >> 6;
    int lane = gid & 63;
    float4 v = ((const float4*)(xb + (size_t)row * NFEAT))[lane];
    Abf[(size_t)row * 64 + lane] = make_uint2(bf16pack(v.x, v.y), bf16pack(v.z, v.w));
    float s = v.x * v.x + v.y * v.y + v.z * v.z + v.w * v.w;
    #pragma unroll
    for (int off = 32; off > 0; off >>= 1) s += __shfl_down(s, off);
    if (lane == 0) a2[row] = s;
}

// ---------------------------------------------------------------------------
// Prep B: w -> bf16 in MFMA-FRAGMENT order + b2.
// Layout: group g (16 cols), sub-block kk (K-slice of 32): 1024-B block where
// byte l*16 holds col g*16+(l&15), bf16 elems kk*32+(l>>4)*8 .. +8.
// A wave's B-fragment load is then ONE coalesced 1024-B global read.
// One wave per group; 8 kk iterations.
// ---------------------------------------------------------------------------
__global__ __launch_bounds__(256) void prep_b_kernel(const float* __restrict__ w,
                                                     uint4* __restrict__ Bfr,
                                                     float* __restrict__ b2) {
    const int t = threadIdx.x, l = t & 63;
    const int g = blockIdx.x * 4 + (t >> 6);        // 0..1023
    const int col = g * 16 + (l & 15);
    const float4* src = (const float4*)w;           // [16384][64] float4
    float ss = 0.f;
    #pragma unroll
    for (int kk = 0; kk < 8; ++kk) {
        float4 v0 = src[(size_t)col * 64 + kk * 8 + (l >> 4) * 2];
        float4 v1 = src[(size_t)col * 64 + kk * 8 + (l >> 4) * 2 + 1];
        ss += v0.x * v0.x + v0.y * v0.y + v0.z * v0.z + v0.w * v0.w
            + v1.x * v1.x + v1.y * v1.y + v1.z * v1.z + v1.w * v1.w;
        uint4 o;
        o.x = bf16pack(v0.x, v0.y);
        o.y = bf16pack(v0.z, v0.w);
        o.z = bf16pack(v1.x, v1.y);
        o.w = bf16pack(v1.z, v1.w);
        Bfr[(size_t)g * 512 + kk * 64 + l] = o;     // uint4 units (16 B)
    }
    ss += __shfl_xor(ss, 16);
    ss += __shfl_xor(ss, 32);
    if (l < 16) b2[g * 16 + l] = ss;
}

// ---------------------------------------------------------------------------
// Main: LDS-free, barrier-free MFMA distance GEMM.
// 512 blocks (2/CU) x 256 thr (4 waves). Wave tile 64 rows x 16 cols; block =
// 256 rows x one 512-col strip (4 waves share B chunks via L1; 4 strips/XCD
// so each XCD's 1 MB B-slice is L2-resident). A panel in 128 pinned VGPRs.
// B streams coalesced global->VGPR, half-chunk (4x1024B) double-buffered —
// compiler emits the counted vmcnt. No LDS, no s_barrier, no lockstep.
// min-dist == max-(dot - b2/2); per-lane top-2, 5-bit chunk id in mantissa.
// ---------------------------------------------------------------------------
__global__ __launch_bounds__(256, 2) void som_mfma_kernel(
        const unsigned short* __restrict__ Abf, const unsigned short* __restrict__ Bfr,
        const float* __restrict__ b2, float* __restrict__ part) {
    const int t = threadIdx.x, l = t & 63;
    const int wid = t >> 6;
    const int x = blockIdx.x & 7, y = blockIdx.x >> 3;
    const int strip = x * 4 + (y & 3);             // 4 strips per XCD
    const int m0 = (y >> 2) * 256 + wid * 64;

    // ---- A panel -> 128 VGPRs (frag layout), pinned ----
    const char* gA = (const char*)Abf + (size_t)(m0 + (l & 15)) * 512 + (l >> 4) * 16;
    bf16x8 afr[4][8];
    #pragma unroll
    for (int m = 0; m < 4; ++m)
        #pragma unroll
        for (int kk = 0; kk < 8; ++kk)
            afr[m][kk] = *(const bf16x8*)(gA + m * 8192 + kk * 64);
    #pragma unroll
    for (int m = 0; m < 4; ++m)
        #pragma unroll
        for (int kk = 0; kk < 8; ++kk)
            asm volatile("" : "+v"(afr[m][kk]));

    const char* gB = (const char*)Bfr + (size_t)strip * (STRIPW * 512) + l * 16;
    const float* b2s = b2 + strip * STRIPW + (l & 15);

    float r0[4][4], r1[4][4];
    #pragma unroll
    for (int m = 0; m < 4; ++m)
        #pragma unroll
        for (int j = 0; j < 4; ++j) { r0[m][j] = -FLT_MAX; r1[m][j] = -FLT_MAX; }

    // prologue: half0 of chunk 0 + its b2
    bf16x8 ba0 = *(const bf16x8*)(gB);
    bf16x8 ba1 = *(const bf16x8*)(gB + 1024);
    bf16x8 ba2 = *(const bf16x8*)(gB + 2048);
    bf16x8 ba3 = *(const bf16x8*)(gB + 3072);
    float b2c = b2s[0];

    for (int c = 0; c < NCH; ++c) {
        const char* base = gB + (size_t)c * 8192;
        // issue half1 loads (consumed after half0 compute)
        bf16x8 bb0 = *(const bf16x8*)(base + 4096);
        bf16x8 bb1 = *(const bf16x8*)(base + 5120);
        bf16x8 bb2 = *(const bf16x8*)(base + 6144);
        bf16x8 bb3 = *(const bf16x8*)(base + 7168);

        const float bi = -0.5f * b2c;
        f32x4 acc[4];
        #pragma unroll
        for (int m = 0; m < 4; ++m) acc[m] = (f32x4){bi, bi, bi, bi};

        #pragma unroll
        for (int m = 0; m < 4; ++m) acc[m] = __builtin_amdgcn_mfma_f32_16x16x32_bf16(afr[m][0], ba0, acc[m], 0, 0, 0);
        #pragma unroll
        for (int m = 0; m < 4; ++m) acc[m] = __builtin_amdgcn_mfma_f32_16x16x32_bf16(afr[m][1], ba1, acc[m], 0, 0, 0);
        #pragma unroll
        for (int m = 0; m < 4; ++m) acc[m] = __builtin_amdgcn_mfma_f32_16x16x32_bf16(afr[m][2], ba2, acc[m], 0, 0, 0);
        #pragma unroll
        for (int m = 0; m < 4; ++m) acc[m] = __builtin_amdgcn_mfma_f32_16x16x32_bf16(afr[m][3], ba3, acc[m], 0, 0, 0);

        // issue half0 loads of next chunk + its b2 (hidden under half1 MFMAs)
        float nb2 = b2c;
        if (c + 1 < NCH) {
            const char* nx = gB + (size_t)(c + 1) * 8192;
            ba0 = *(const bf16x8*)(nx);
            ba1 = *(const bf16x8*)(nx + 1024);
            ba2 = *(const bf16x8*)(nx + 2048);
            ba3 = *(const bf16x8*)(nx + 3072);
            nb2 = b2s[(c + 1) * 16];
        }

        #pragma unroll
        for (int m = 0; m < 4; ++m) acc[m] = __builtin_amdgcn_mfma_f32_16x16x32_bf16(afr[m][4], bb0, acc[m], 0, 0, 0);
        #pragma unroll
        for (int m = 0; m < 4; ++m) acc[m] = __builtin_amdgcn_mfma_f32_16x16x32_bf16(afr[m][5], bb1, acc[m], 0, 0, 0);
        #pragma unroll
        for (int m = 0; m < 4; ++m) acc[m] = __builtin_amdgcn_mfma_f32_16x16x32_bf16(afr[m][6], bb2, acc[m], 0, 0, 0);
        #pragma unroll
        for (int m = 0; m < 4; ++m) acc[m] = __builtin_amdgcn_mfma_f32_16x16x32_bf16(afr[m][7], bb3, acc[m], 0, 0, 0);

        // top-2 fold: 5-bit chunk id in low mantissa bits (3 VALU/elem)
        const unsigned idn = (unsigned)c;
        #pragma unroll
        for (int m = 0; m < 4; ++m)
            #pragma unroll
            for (int j = 0; j < 4; ++j) {
                float p = __uint_as_float((__float_as_uint(acc[m][j]) & 0xFFFFFFE0u) | idn);
                float nr1 = __builtin_amdgcn_fmed3f(r0[m][j], r1[m][j], p);
                r0[m][j] = fmaxf(r0[m][j], p);
                r1[m][j] = nr1;
            }
        b2c = nb2;
    }

    // ---- per-row merge over 16 lane-cols (repack 9-bit id); write part ----
    #pragma unroll
    for (int m = 0; m < 4; ++m)
        #pragma unroll
        for (int j = 0; j < 4; ++j) {
            unsigned u0 = __float_as_uint(r0[m][j]);
            unsigned u1 = __float_as_uint(r1[m][j]);
            u0 = (u0 & 0xFFFFFC00u) | ((u0 & 31u) << 4) | (unsigned)(l & 15);
            u1 = (u1 & 0xFFFFFC00u) | ((u1 & 31u) << 4) | (unsigned)(l & 15);
            float v0 = __uint_as_float(u0), v1 = __uint_as_float(u1);
            #pragma unroll
            for (int off = 1; off < 16; off <<= 1) {
                float o0 = __shfl_xor(v0, off), o1 = __shfl_xor(v1, off);
                float nv1 = fmaxf(fminf(v0, o0), fmaxf(v1, o1));
                v0 = fmaxf(v0, o0);
                v1 = nv1;
            }
            if ((l & 15) == 0) {
                int row = m0 + m * 16 + (l >> 4) * 4 + j;
                ((float2*)part)[(size_t)row * NSTRIP + strip] = make_float2(v0, v1);
            }
        }
}

// ---------------------------------------------------------------------------
// Refine: 1 wave per row over 64 packed entries (32 strips x top-2); exact
// fp32+sqrt recompute of candidates within margin; (dist, idx) argmin.
// ---------------------------------------------------------------------------
__global__ __launch_bounds__(256) void refine_kernel(
        const float* __restrict__ xb, const float* __restrict__ w,
        const float* __restrict__ a2, const float* __restrict__ b2,
        const float* __restrict__ part, int* __restrict__ out) {
    const int t = threadIdx.x, l = t & 63;
    const int row = blockIdx.x * 4 + (t >> 6);

    const float v = part[(size_t)row * (NSTRIP * 2) + l];
    float mx = v;
    #pragma unroll
    for (int off = 1; off < 64; off <<= 1) mx = fmaxf(mx, __shfl_xor(mx, off));
    const float cut = mx - UMARGIN;

    unsigned long long key = ~0ull;
    if (v >= cut) {
        unsigned b = __float_as_uint(v);
        int lane4 = b & 15, ch = (b >> 4) & 31, strip = l >> 1;
        int col = strip * STRIPW + ch * 16 + lane4;
        const float4* xr = (const float4*)(xb + (size_t)row * NFEAT);
        const float4* wr = (const float4*)(w + (size_t)col * NFEAT);
        float s0 = 0.f, s1 = 0.f, s2 = 0.f, s3 = 0.f;
        #pragma unroll
        for (int k = 0; k < 16; ++k) {
            float4 x0 = xr[4 * k + 0], w0 = wr[4 * k + 0];
            float4 x1 = xr[4 * k + 1], w1 = wr[4 * k + 1];
            float4 x2 = xr[4 * k + 2], w2 = wr[4 * k + 2];
            float4 x3 = xr[4 * k + 3], w3 = wr[4 * k + 3];
            s0 += x0.x * w0.x + x0.y * w0.y + x0.z * w0.z + x0.w * w0.w;
            s1 += x1.x * w1.x + x1.y * w1.y + x1.z * w1.z + x1.w * w1.w;
            s2 += x2.x * w2.x + x2.y * w2.y + x2.z * w2.z + x2.w * w2.w;
            s3 += x3.x * w3.x + x3.y * w3.y + x3.z * w3.z + x3.w * w3.w;
        }
        float dot = (s0 + s1) + (s2 + s3);
        float dd = a2[row] + b2[col] - 2.f * dot;
        float s = sqrtf(fmaxf(dd, 0.f));
        key = ((unsigned long long)__float_as_uint(s) << 32) | (unsigned)col;
    }
    #pragma unroll
    for (int off = 1; off < 64; off <<= 1) {
        unsigned long long o = __shfl_xor(key, off);
        key = o < key ? o : key;
    }
    if (l == 0) {
        int idx = (int)(key & 0xffffffffu);
        out[2 * row]     = idx >> 7;
        out[2 * row + 1] = idx & 127;
    }
}

extern "C" void kernel_launch(void* const* d_in, const int* in_sizes, int n_in,
                              void* d_out, int out_size, void* d_ws, size_t ws_size,
                              hipStream_t stream) {
    const float* xb = (const float*)d_in[0];   // (4096, 256)
    const float* w  = (const float*)d_in[1];   // (16384, 256)
    int* out = (int*)d_out;

    char* ws = (char*)d_ws;
    unsigned short* Abf = (unsigned short*)ws;                 // 2 MB
    unsigned short* Bfr = (unsigned short*)(ws + (2u << 20));  // 8 MB (frag order)
    float* a2   = (float*)(ws + (10u << 20));                  // 16 KB
    float* b2   = (float*)(ws + (10u << 20) + (64u << 10));    // 64 KB
    float* part = (float*)(ws + (10u << 20) + (128u << 10));   // 1 MB

    prep_a_kernel<<<(BATCH * 64) / 256, 256, 0, stream>>>(xb, (uint2*)Abf, a2);
    prep_b_kernel<<<MTOT / 64, 256, 0, stream>>>(w, (uint4*)Bfr, b2);
    som_mfma_kernel<<<512, 256, 0, stream>>>(Abf, Bfr, b2, part);
    refine_kernel<<<BATCH / 4, 256, 0, stream>>>(xb, w, a2, b2, part, out);
}